// Round 4
// baseline (265.104 us; speedup 1.0000x reference)
//
#include <hip/hip_runtime.h>
#include <hip/hip_cooperative_groups.h>
#include <math.h>

namespace cg = cooperative_groups;

#define NT    300
#define NA    3
#define BATCH 16
#define NCLS  80
#define CCH   85
#define NCHUNK 394            // obj chunks of 1024 cells: 300 (L0) + 75 (L1) + 19 (L2)
#define NBLK   675            // one block per 4 target rows; blocks <394 also do an obj chunk
// fallback (round-3 proven) geometry:
#define NBO   394
#define NBT   675

// ws layout (byte offsets) — every slot written unconditionally, so NO
// pre-zeroing is needed; harness may poison ws each iteration:
//   0     : double obj_part[394]      per-obj-chunk softplus partial
//   3200  : double tgt_part[675][4]   per-block {lbox, lcls, nval, objcorr}
// total 24800 B. The last-wins scatter winner is a pure function of
// targets+anchors, so each target wave decides winner-ship locally by
// scanning later targets of the same (layer, anchor).

__device__ __forceinline__ float softplusf(float x) {
    // == max(x,0) + log1p(exp(-|x|)) == bce(x, 0)
    return fmaxf(x, 0.f) + log1pf(expf(-fabsf(x)));
}

// 256-thread block reduce; result valid on thread 0. Trailing barrier makes
// repeated calls safe (WAR on red[]).
__device__ __forceinline__ double block_reduce(double v, double* red) {
    #pragma unroll
    for (int off = 32; off > 0; off >>= 1) v += __shfl_down(v, off, 64);
    const int wid = threadIdx.x >> 6, lane = threadIdx.x & 63;
    if (lane == 0) red[wid] = v;
    __syncthreads();
    double r = (threadIdx.x < 4) ? red[threadIdx.x] : 0.0;
    r += __shfl_down(r, 2, 64);
    r += __shfl_down(r, 1, 64);
    __syncthreads();
    return r;
}

// 64-lane wave reduce (no barriers)
__device__ __forceinline__ double wred(double v) {
    #pragma unroll
    for (int off = 32; off > 0; off >>= 1) v += __shfl_down(v, off, 64);
    return v;
}

// ---------------- shared target-row routine (one wave = one row) -----------
// Computes this row's {lbox, lcls, nval, objcorr} contributions; valid on lane 0.
__device__ __forceinline__ void target_row(
    int gr, int lane,
    const float* __restrict__ p0, const float* __restrict__ p1,
    const float* __restrict__ p2,
    const float* __restrict__ targets, const float* __restrict__ anchors,
    float out4[4])
{
    const int li = gr / (NA * NT);
    const int r  = gr - li * (NA * NT);                 // a*NT + ti
    const int a  = r / NT;
    const int ti = r - a * NT;
    const float* p = (li == 0) ? p0 : ((li == 1) ? p1 : p2);
    const int W = 80 >> li, H = W;

    // wave-uniform scalars (broadcast loads)
    const float img = targets[ti*6 + 0];
    const float cls = targets[ti*6 + 1];
    const float tx  = targets[ti*6 + 2] * (float)W;
    const float ty  = targets[ti*6 + 3] * (float)H;
    const float tw  = targets[ti*6 + 4] * (float)W;
    const float th  = targets[ti*6 + 5] * (float)H;

    const float ax = anchors[(li*3 + a)*2 + 0];
    const float ay = anchors[(li*3 + a)*2 + 1];
    const float rx = tw / ax, ry = th / ay;
    const float mr = fmaxf(fmaxf(rx, 1.f/rx), fmaxf(ry, 1.f/ry));
    const bool  mask = mr < 4.f;
    const float mf = mask ? 1.f : 0.f;

    const int b = (int)img;
    const int c = (int)cls;
    const int gij_x = (int)tx;          // trunc == floor (positive)
    const int gij_y = (int)ty;
    const int gi = min(max(gij_x, 0), W - 1);
    const int gj = min(max(gij_y, 0), H - 1);

    // last-wins dedup, recomputed locally: row loses iff some later target tj
    // (same layer+anchor+image) is masked-in and lands in the same cell.
    // targets is 7.2 KB -> L1-resident; ~5 iters/lane; float2 loads (8B-aligned).
    bool beaten = false;
    for (int tj = ti + 1 + lane; tj < NT; tj += 64) {
        const float2 tA = *(const float2*)(targets + tj*6 + 0); // img, cls
        const float2 tB = *(const float2*)(targets + tj*6 + 2); // x, y
        const float2 tC = *(const float2*)(targets + tj*6 + 4); // w, h
        const float xj = tB.x * (float)W, yj = tB.y * (float)H;
        const float wj = tC.x * (float)W, hj = tC.y * (float)H;
        const float rxj = wj / ax, ryj = hj / ay;
        const float mrj = fmaxf(fmaxf(rxj, 1.f/rxj), fmaxf(ryj, 1.f/ryj));
        if (mrj < 4.f && tA.x == img) {
            const int gi_j = min(max((int)xj, 0), W - 1);
            const int gj_j = min(max((int)yj, 0), H - 1);
            if (gi_j == gi && gj_j == gj) beaten = true;
        }
    }
    const bool winner = mask && !__any(beaten);

    // reference quirk: anch = anchors[a, a] (layer-independent)
    const float anch_x = anchors[(a*3 + a)*2 + 0];
    const float anch_y = anchors[(a*3 + a)*2 + 1];

    const int match = BATCH - 1 - b;
    const int cell  = ((match*NA + a)*H + gj)*W + gi;
    const float* ps = p + (size_t)cell * CCH;

    // coalesced: 2 wave-load instructions cover all 85 channels
    const float x1 = ps[lane];                                // ch 0..63
    const float x2 = (lane < CCH - 64) ? ps[64 + lane] : 0.f; // ch 64..84

    const float s0   = __shfl(x1, 0);
    const float s1   = __shfl(x1, 1);
    const float s2   = __shfl(x1, 2);
    const float s3   = __shfl(x1, 3);
    const float objx = __shfl(x1, 4);

    // cls: sum_k softplus(ps[5+k]) - ps[5+c]
    const int ch = 5 + c;
    float contrib = (lane >= 5) ? softplusf(x1) : 0.f;
    if (lane < CCH - 64) contrib += softplusf(x2);
    if (lane == ch) contrib -= x1;
    if (ch >= 64 && lane == ch - 64) contrib -= x2;
    #pragma unroll
    for (int off = 32; off > 0; off >>= 1)
        contrib += __shfl_down(contrib, off, 64);             // lane 0 has sum

    // box math (wave-uniform)
    const float pxx = 1.f / (1.f + expf(-s0));
    const float pyy = 1.f / (1.f + expf(-s1));
    const float pw  = expf(s2) * anch_x;
    const float ph  = expf(s3) * anch_y;
    const float fx  = tx - (float)gij_x;
    const float fy  = ty - (float)gij_y;

    const float eps = 1e-9f;
    const float b1x1 = pxx - pw*0.5f, b1x2 = pxx + pw*0.5f;
    const float b1y1 = pyy - ph*0.5f, b1y2 = pyy + ph*0.5f;
    const float b2x1 = fx - tw*0.5f,  b2x2 = fx + tw*0.5f;
    const float b2y1 = fy - th*0.5f,  b2y2 = fy + th*0.5f;
    float iw = fminf(b1x2, b2x2) - fmaxf(b1x1, b2x1); iw = fmaxf(iw, 0.f);
    float ih = fminf(b1y2, b2y2) - fmaxf(b1y1, b2y1); ih = fmaxf(ih, 0.f);
    const float inter = iw * ih;
    const float w1 = b1x2 - b1x1, h1 = b1y2 - b1y1 + eps;
    const float w2 = b2x2 - b2x1, h2 = b2y2 - b2y1 + eps;
    const float uni = w1*h1 + w2*h2 - inter + eps;
    const float iou = inter / uni;
    const float cw  = fmaxf(b1x2, b2x2) - fminf(b1x1, b2x1);
    const float chh = fmaxf(b1y2, b2y2) - fminf(b1y1, b2y1);
    const float c2 = cw*cw + chh*chh + eps;
    const float dx = b2x1 + b2x2 - b1x1 - b1x2;
    const float dy = b2y1 + b2y2 - b1y1 - b1y2;
    const float rho2 = (dx*dx + dy*dy) * 0.25f;
    const float dat = atanf(w2/h2) - atanf(w1/h1);
    const float v = 0.40528473456935108577f * dat * dat;      // 4/pi^2
    const float alpha = v / (1.f + eps - iou + v);
    const float ciou = iou - (rho2/c2 + v*alpha);

    out4[0] = (1.f - ciou) * mf;
    out4[1] = contrib * mf;
    out4[2] = mf;
    out4[3] = winner ? objx * fmaxf(ciou, 0.f) : 0.f;
}

// ---------------- single cooperative kernel --------------------------------
__global__ __launch_bounds__(256, 3) void fused_kernel(
    const float* __restrict__ p0, const float* __restrict__ p1,
    const float* __restrict__ p2,
    const float* __restrict__ targets, const float* __restrict__ anchors,
    char* __restrict__ ws, float* __restrict__ out)
{
    __shared__ double red[4];
    __shared__ double acc[4][4];   // [wave][quantity: lb, lc, nv, co]

    double* obj_part = (double*)ws;
    double* tgt_part = (double*)(ws + 3200);

    const int tb   = blockIdx.x;
    const int wid  = threadIdx.x >> 6;
    const int lane = threadIdx.x & 63;

    // obj gathers issued FIRST so their HBM latency hides under target math
    float s = 0.f;
    if (tb < NCHUNK) {
        int li, bb;
        if (tb < 300)      { li = 0; bb = tb; }
        else if (tb < 375) { li = 1; bb = tb - 300; }
        else               { li = 2; bb = tb - 375; }
        const float* p = (li == 0) ? p0 : ((li == 1) ? p1 : p2);
        const int N = (BATCH * NA * 6400) >> (2*li);   // 307200/76800/19200
        #pragma unroll
        for (int k = 0; k < 4; ++k) {
            const int idx = bb * 1024 + k * 256 + threadIdx.x;
            if (idx < N) s += softplusf(p[(size_t)idx * CCH + 4]);
        }
    }

    // target row (one per wave)
    float o4[4];
    target_row(tb*4 + wid, lane, p0, p1, p2, targets, anchors, o4);
    if (lane == 0) {
        acc[wid][0] = (double)o4[0];
        acc[wid][1] = (double)o4[1];
        acc[wid][2] = (double)o4[2];
        acc[wid][3] = (double)o4[3];
    }

    // obj block reduce (block-uniform; harmless zeros for tb>=NCHUNK)
    const double t = block_reduce((double)s, red);
    if (tb < NCHUNK && threadIdx.x == 0) obj_part[tb] = t;

    __syncthreads();
    if (threadIdx.x < 4)       // unconditional partial write (poison-proof)
        tgt_part[tb*4 + threadIdx.x] =
            acc[0][threadIdx.x] + acc[1][threadIdx.x] +
            acc[2][threadIdx.x] + acc[3][threadIdx.x];

    cg::this_grid().sync();    // device-scope release/acquire: cross-XCD safe

    // single-wave finalize (block 0, wave 0) — barrier-free
    if (blockIdx.x == 0 && threadIdx.x < 64) {
        double so0=0,so1=0,so2=0;
        double lb0=0,lb1=0,lb2=0, lc0=0,lc1=0,lc2=0;
        double nv0=0,nv1=0,nv2=0, co0=0,co1=0,co2=0;
        for (int bk = lane; bk < NCHUNK; bk += 64) {
            const double v = obj_part[bk];
            if (bk < 300)      so0 += v;
            else if (bk < 375) so1 += v;
            else               so2 += v;
        }
        // 4 rows per block, all same layer: q<225 -> L0, q<450 -> L1, else L2
        for (int q = lane; q < NBLK; q += 64) {
            const double a0 = tgt_part[q*4+0], a1 = tgt_part[q*4+1];
            const double a2 = tgt_part[q*4+2], a3 = tgt_part[q*4+3];
            if (q < 225)      { lb0+=a0; lc0+=a1; nv0+=a2; co0+=a3; }
            else if (q < 450) { lb1+=a0; lc1+=a1; nv1+=a2; co1+=a3; }
            else              { lb2+=a0; lc2+=a1; nv2+=a2; co2+=a3; }
        }
        so0=wred(so0); so1=wred(so1); so2=wred(so2);
        lb0=wred(lb0); lb1=wred(lb1); lb2=wred(lb2);
        lc0=wred(lc0); lc1=wred(lc1); lc2=wred(lc2);
        nv0=wred(nv0); nv1=wred(nv1); nv2=wred(nv2);
        co0=wred(co0); co1=wred(co1); co2=wred(co2);
        if (lane == 0) {
            const double so[3]={so0,so1,so2}, lb[3]={lb0,lb1,lb2};
            const double lc[3]={lc0,lc1,lc2}, nv[3]={nv0,nv1,nv2};
            const double co[3]={co0,co1,co2};
            double lbox = 0.0, lobj = 0.0, lcls = 0.0;
            #pragma unroll
            for (int l = 0; l < 3; ++l) {
                const double nvv = fmax(nv[l], 1.0);
                lbox += lb[l] / nvv;
                lcls += lc[l] / (nvv * (double)NCLS);
                const double N = (double)((BATCH * NA * 6400) >> (2*l));
                lobj += (so[l] - co[l]) / N;
            }
            lbox *= 0.05;
            lcls *= 0.5;
            const double loss = lbox + lobj + lcls;
            out[0] = (float)loss;
            out[1] = (float)lbox;
            out[2] = (float)lobj;
            out[3] = (float)lcls;
            out[4] = (float)loss;
        }
    }
}

// ---------------- fallback: round-3 proven two-kernel path -----------------
__global__ __launch_bounds__(256) void main_kernel(
    const float* __restrict__ p0, const float* __restrict__ p1,
    const float* __restrict__ p2,
    const float* __restrict__ targets, const float* __restrict__ anchors,
    char* __restrict__ ws)
{
    __shared__ double red[4];
    __shared__ double acc[4][4];
    double* obj_part = (double*)ws;
    double* tgt_part = (double*)(ws + 3200);

    if (blockIdx.x < NBO) {
        const int ob = blockIdx.x;
        int li, bb;
        if (ob < 300)      { li = 0; bb = ob; }
        else if (ob < 375) { li = 1; bb = ob - 300; }
        else               { li = 2; bb = ob - 375; }
        const float* p = (li == 0) ? p0 : ((li == 1) ? p1 : p2);
        const int N = (BATCH * NA * 6400) >> (2*li);
        float s = 0.f;
        #pragma unroll
        for (int k = 0; k < 4; ++k) {
            const int idx = bb * 1024 + k * 256 + threadIdx.x;
            if (idx < N) s += softplusf(p[(size_t)idx * CCH + 4]);
        }
        const double t = block_reduce((double)s, red);
        if (threadIdx.x == 0) obj_part[ob] = t;
        return;
    }
    const int tb = blockIdx.x - NBO;
    float o4[4];
    target_row(tb*4 + (threadIdx.x >> 6), threadIdx.x & 63,
               p0, p1, p2, targets, anchors, o4);
    const int wid = threadIdx.x >> 6;
    if ((threadIdx.x & 63) == 0) {
        acc[wid][0] = (double)o4[0]; acc[wid][1] = (double)o4[1];
        acc[wid][2] = (double)o4[2]; acc[wid][3] = (double)o4[3];
    }
    __syncthreads();
    if (threadIdx.x < 4)
        tgt_part[tb*4 + threadIdx.x] =
            acc[0][threadIdx.x] + acc[1][threadIdx.x] +
            acc[2][threadIdx.x] + acc[3][threadIdx.x];
}

__global__ __launch_bounds__(256) void final_kernel(
    const char* __restrict__ ws, float* __restrict__ out)
{
    __shared__ double red[4];
    const double* obj_part = (const double*)ws;
    const double* tgt_part = (const double*)(ws + 3200);

    double so[3] = {0,0,0};
    double lb[3] = {0,0,0}, lc[3] = {0,0,0}, nv[3] = {0,0,0}, co[3] = {0,0,0};
    for (int bk = threadIdx.x; bk < NBO; bk += 256) {
        const int l = (bk < 300) ? 0 : ((bk < 375) ? 1 : 2);
        so[l] += obj_part[bk];
    }
    for (int tb = threadIdx.x; tb < NBT; tb += 256) {
        const int l = (tb < 225) ? 0 : ((tb < 450) ? 1 : 2);
        lb[l] += tgt_part[tb*4 + 0];
        lc[l] += tgt_part[tb*4 + 1];
        nv[l] += tgt_part[tb*4 + 2];
        co[l] += tgt_part[tb*4 + 3];
    }
    double rsum[15];
    #pragma unroll
    for (int l = 0; l < 3; ++l) {
        rsum[l*5 + 0] = block_reduce(lb[l], red);
        rsum[l*5 + 1] = block_reduce(lc[l], red);
        rsum[l*5 + 2] = block_reduce(co[l], red);
        rsum[l*5 + 3] = block_reduce(nv[l], red);
        rsum[l*5 + 4] = block_reduce(so[l], red);
    }
    if (threadIdx.x == 0) {
        double lbox = 0.0, lobj = 0.0, lcls = 0.0;
        for (int l = 0; l < 3; ++l) {
            const double nvv = fmax(rsum[l*5 + 3], 1.0);
            lbox += rsum[l*5 + 0] / nvv;
            lcls += rsum[l*5 + 1] / (nvv * (double)NCLS);
            const double N = (double)((BATCH * NA * 6400) >> (2*l));
            lobj += (rsum[l*5 + 4] - rsum[l*5 + 2]) / N;
        }
        lbox *= 0.05;
        lcls *= 0.5;
        const double loss = lbox + lobj + lcls;
        out[0] = (float)loss;
        out[1] = (float)lbox;
        out[2] = (float)lobj;
        out[3] = (float)lcls;
        out[4] = (float)loss;
    }
}

extern "C" void kernel_launch(void* const* d_in, const int* in_sizes, int n_in,
                              void* d_out, int out_size, void* d_ws, size_t ws_size,
                              hipStream_t stream) {
    const float* p0      = (const float*)d_in[0];
    const float* p1      = (const float*)d_in[1];
    const float* p2      = (const float*)d_in[2];
    const float* targets = (const float*)d_in[3];
    const float* anchors = (const float*)d_in[4];
    char*  ws  = (char*)d_ws;
    float* out = (float*)d_out;

    void* args[7] = {(void*)&p0, (void*)&p1, (void*)&p2,
                     (void*)&targets, (void*)&anchors,
                     (void*)&ws, (void*)&out};
    const hipError_t e = hipLaunchCooperativeKernel(
        fused_kernel, dim3(NBLK), dim3(256), args, 0, stream);
    if (e != hipSuccess) {
        // capture-safe fallback: proven round-3 two-kernel path
        main_kernel<<<NBO + NBT, 256, 0, stream>>>(p0, p1, p2, targets,
                                                   anchors, ws);
        final_kernel<<<1, 256, 0, stream>>>(ws, out);
    }
}

// Round 5
// 176.912 us; speedup vs baseline: 1.4985x; 1.4985x over previous
//
#include <hip/hip_runtime.h>
#include <math.h>

#define NT    300
#define NA    3
#define BATCH 16
#define NCLS  80
#define CCH   85
#define NBO   394             // obj blocks: 300 (L0) + 75 (L1) + 19 (L2)
#define NBT   675             // target blocks: 4 waves/block, one ROW per WAVE
#define NBLK  (NBO + NBT)

// ws layout (byte offsets) — every slot written unconditionally by main_kernel,
// so NO pre-zeroing (and no memset dispatch) is needed; harness may poison ws:
//   0     : double obj_part[394]      per-obj-block softplus partial
//   3200  : double tgt_part[675][4]   per-target-block {lbox, lcls, nval, objcorr}
// total 24800 B. No row arrays, no hash table: the last-wins winner of a
// scatter cell is a pure function of targets+anchors, so each target wave
// decides winner-ship locally by scanning later targets of the same anchor.
//
// Timing model (R0/R3/R4 cross-round arithmetic): ~100 us fixed harness reset
// machinery + 63.5 us ws-poison fill + ~10-14 us for these two kernels. Only
// the last term is kernel-controllable.

__device__ __forceinline__ float softplusf(float x) {
    // == max(x,0) + log1p(exp(-|x|)) == bce(x, 0)
    return fmaxf(x, 0.f) + log1pf(expf(-fabsf(x)));
}

// 256-thread block reduce; result valid on thread 0. Trailing barrier makes
// repeated calls safe (WAR on red[]).
__device__ __forceinline__ double block_reduce(double v, double* red) {
    #pragma unroll
    for (int off = 32; off > 0; off >>= 1) v += __shfl_down(v, off, 64);
    const int wid = threadIdx.x >> 6, lane = threadIdx.x & 63;
    if (lane == 0) red[wid] = v;
    __syncthreads();
    double r = (threadIdx.x < 4) ? red[threadIdx.x] : 0.0;
    r += __shfl_down(r, 2, 64);
    r += __shfl_down(r, 1, 64);
    __syncthreads();
    return r;
}

// 64-lane wave reduce (no barriers)
__device__ __forceinline__ double wred(double v) {
    #pragma unroll
    for (int off = 32; off > 0; off >>= 1) v += __shfl_down(v, off, 64);
    return v;
}

__global__ __launch_bounds__(256) void main_kernel(
    const float* __restrict__ p0, const float* __restrict__ p1,
    const float* __restrict__ p2,
    const float* __restrict__ targets, const float* __restrict__ anchors,
    char* __restrict__ ws)
{
    __shared__ double red[4];
    __shared__ double acc[4][4];   // [wave][quantity: lb, lc, nv, co]

    double* obj_part = (double*)ws;
    double* tgt_part = (double*)(ws + 3200);

    if (blockIdx.x < NBO) {
        // ---------- obj softplus sweep: 4 independent gathers/thread --------
        const int ob = blockIdx.x;
        int li, bb;
        if (ob < 300)      { li = 0; bb = ob; }
        else if (ob < 375) { li = 1; bb = ob - 300; }
        else               { li = 2; bb = ob - 375; }
        const float* p = (li == 0) ? p0 : ((li == 1) ? p1 : p2);
        const int N = (BATCH * NA * 6400) >> (2*li);   // 307200/76800/19200

        float s = 0.f;
        #pragma unroll
        for (int k = 0; k < 4; ++k) {
            const int idx = bb * 1024 + k * 256 + threadIdx.x;
            if (idx < N) s += softplusf(p[(size_t)idx * CCH + 4]);
        }
        const double t = block_reduce((double)s, red);
        if (threadIdx.x == 0) obj_part[ob] = t;
        return;
    }

    // ---------- per-target math: ONE ROW PER WAVE ---------------------------
    const int tb   = blockIdx.x - NBO;
    const int gr   = tb * 4 + (threadIdx.x >> 6);         // global row
    const int lane = threadIdx.x & 63;
    const int li   = gr / (NA * NT);
    const int r    = gr - li * (NA * NT);                 // a*NT + ti
    const int a    = r / NT;
    const int ti   = r - a * NT;
    const float* p = (li == 0) ? p0 : ((li == 1) ? p1 : p2);
    const int W = 80 >> li, H = W;

    // wave-uniform scalars (broadcast loads)
    const float img = targets[ti*6 + 0];
    const float cls = targets[ti*6 + 1];
    const float tx  = targets[ti*6 + 2] * (float)W;
    const float ty  = targets[ti*6 + 3] * (float)H;
    const float tw  = targets[ti*6 + 4] * (float)W;
    const float th  = targets[ti*6 + 5] * (float)H;

    const float ax = anchors[(li*3 + a)*2 + 0];
    const float ay = anchors[(li*3 + a)*2 + 1];
    const float rx = tw / ax, ry = th / ay;
    const float mr = fmaxf(fmaxf(rx, 1.f/rx), fmaxf(ry, 1.f/ry));
    const bool  mask = mr < 4.f;
    const float mf = mask ? 1.f : 0.f;

    const int b = (int)img;
    const int c = (int)cls;
    const int gij_x = (int)tx;          // trunc == floor (positive)
    const int gij_y = (int)ty;
    const int gi = min(max(gij_x, 0), W - 1);
    const int gj = min(max(gij_y, 0), H - 1);

    // reference quirk: anch = anchors[a, a] (layer-independent)
    const float anch_x = anchors[(a*3 + a)*2 + 0];
    const float anch_y = anchors[(a*3 + a)*2 + 1];

    const int match = BATCH - 1 - b;
    const int cell  = ((match*NA + a)*H + gj)*W + gi;
    const float* ps = p + (size_t)cell * CCH;

    // ISSUE the two big coalesced wave-loads EARLY: their HBM/L2 latency
    // overlaps the L1-resident dedup scan below.
    const float x1 = ps[lane];                                // ch 0..63
    const float x2 = (lane < CCH - 64) ? ps[64 + lane] : 0.f; // ch 64..84

    // last-wins dedup, recomputed locally: row loses iff some later target tj
    // (same layer+anchor+image) is masked-in and lands in the same cell.
    // targets is 7.2 KB -> L1-resident; ~5 iters/lane; float2 loads.
    bool beaten = false;
    for (int tj = ti + 1 + lane; tj < NT; tj += 64) {
        const float2 tA = *(const float2*)(targets + tj*6 + 0); // img, cls
        const float2 tB = *(const float2*)(targets + tj*6 + 2); // x, y
        const float2 tC = *(const float2*)(targets + tj*6 + 4); // w, h
        const float xj = tB.x * (float)W, yj = tB.y * (float)H;
        const float wj = tC.x * (float)W, hj = tC.y * (float)H;
        const float rxj = wj / ax, ryj = hj / ay;
        const float mrj = fmaxf(fmaxf(rxj, 1.f/rxj), fmaxf(ryj, 1.f/ryj));
        if (mrj < 4.f && tA.x == img) {
            const int gi_j = min(max((int)xj, 0), W - 1);
            const int gj_j = min(max((int)yj, 0), H - 1);
            if (gi_j == gi && gj_j == gj) beaten = true;
        }
    }
    const bool winner = mask && !__any(beaten);

    const float s0   = __shfl(x1, 0);
    const float s1   = __shfl(x1, 1);
    const float s2   = __shfl(x1, 2);
    const float s3   = __shfl(x1, 3);
    const float objx = __shfl(x1, 4);

    // cls: sum_k softplus(ps[5+k]) - ps[5+c]
    const int ch = 5 + c;
    float contrib = (lane >= 5) ? softplusf(x1) : 0.f;
    if (lane < CCH - 64) contrib += softplusf(x2);
    if (lane == ch) contrib -= x1;
    if (ch >= 64 && lane == ch - 64) contrib -= x2;
    #pragma unroll
    for (int off = 32; off > 0; off >>= 1)
        contrib += __shfl_down(contrib, off, 64);             // lane 0 has sum

    // box math (wave-uniform)
    const float pxx = 1.f / (1.f + expf(-s0));
    const float pyy = 1.f / (1.f + expf(-s1));
    const float pw  = expf(s2) * anch_x;
    const float ph  = expf(s3) * anch_y;
    const float fx  = tx - (float)gij_x;
    const float fy  = ty - (float)gij_y;

    const float eps = 1e-9f;
    const float b1x1 = pxx - pw*0.5f, b1x2 = pxx + pw*0.5f;
    const float b1y1 = pyy - ph*0.5f, b1y2 = pyy + ph*0.5f;
    const float b2x1 = fx - tw*0.5f,  b2x2 = fx + tw*0.5f;
    const float b2y1 = fy - th*0.5f,  b2y2 = fy + th*0.5f;
    float iw = fminf(b1x2, b2x2) - fmaxf(b1x1, b2x1); iw = fmaxf(iw, 0.f);
    float ih = fminf(b1y2, b2y2) - fmaxf(b1y1, b2y1); ih = fmaxf(ih, 0.f);
    const float inter = iw * ih;
    const float w1 = b1x2 - b1x1, h1 = b1y2 - b1y1 + eps;
    const float w2 = b2x2 - b2x1, h2 = b2y2 - b2y1 + eps;
    const float uni = w1*h1 + w2*h2 - inter + eps;
    const float iou = inter / uni;
    const float cw  = fmaxf(b1x2, b2x2) - fminf(b1x1, b2x1);
    const float chh = fmaxf(b1y2, b2y2) - fminf(b1y1, b2y1);
    const float c2 = cw*cw + chh*chh + eps;
    const float dx = b2x1 + b2x2 - b1x1 - b1x2;
    const float dy = b2y1 + b2y2 - b1y1 - b1y2;
    const float rho2 = (dx*dx + dy*dy) * 0.25f;
    const float dat = atanf(w2/h2) - atanf(w1/h1);
    const float v = 0.40528473456935108577f * dat * dat;      // 4/pi^2
    const float alpha = v / (1.f + eps - iou + v);
    const float ciou = iou - (rho2/c2 + v*alpha);

    if (lane == 0) {
        const int wid = threadIdx.x >> 6;
        acc[wid][0] = (double)((1.f - ciou) * mf);
        acc[wid][1] = (double)(contrib * mf);
        acc[wid][2] = (double)mf;
        acc[wid][3] = winner ? (double)(objx * fmaxf(ciou, 0.f)) : 0.0;
    }
    __syncthreads();
    // unconditional write of this block's 4 partials (poison-proof)
    if (threadIdx.x < 4) {
        tgt_part[tb*4 + threadIdx.x] =
            acc[0][threadIdx.x] + acc[1][threadIdx.x] +
            acc[2][threadIdx.x] + acc[3][threadIdx.x];
    }
}

// single-wave barrier-free finalize (structure proven bit-correct in R4)
__global__ __launch_bounds__(64) void final_kernel(
    const char* __restrict__ ws, float* __restrict__ out)
{
    const double* obj_part = (const double*)ws;
    const double* tgt_part = (const double*)(ws + 3200);
    const int lane = threadIdx.x;

    double so0=0,so1=0,so2=0;
    double lb0=0,lb1=0,lb2=0, lc0=0,lc1=0,lc2=0;
    double nv0=0,nv1=0,nv2=0, co0=0,co1=0,co2=0;

    for (int bk = lane; bk < NBO; bk += 64) {
        const double v = obj_part[bk];
        if (bk < 300)      so0 += v;
        else if (bk < 375) so1 += v;
        else               so2 += v;
    }
    // 4 rows per block, all same layer: q<225 -> L0, q<450 -> L1, else L2
    for (int q = lane; q < NBT; q += 64) {
        const double a0 = tgt_part[q*4+0], a1 = tgt_part[q*4+1];
        const double a2 = tgt_part[q*4+2], a3 = tgt_part[q*4+3];
        if (q < 225)      { lb0+=a0; lc0+=a1; nv0+=a2; co0+=a3; }
        else if (q < 450) { lb1+=a0; lc1+=a1; nv1+=a2; co1+=a3; }
        else              { lb2+=a0; lc2+=a1; nv2+=a2; co2+=a3; }
    }
    so0=wred(so0); so1=wred(so1); so2=wred(so2);
    lb0=wred(lb0); lb1=wred(lb1); lb2=wred(lb2);
    lc0=wred(lc0); lc1=wred(lc1); lc2=wred(lc2);
    nv0=wred(nv0); nv1=wred(nv1); nv2=wred(nv2);
    co0=wred(co0); co1=wred(co1); co2=wred(co2);

    if (lane == 0) {
        const double so[3]={so0,so1,so2}, lb[3]={lb0,lb1,lb2};
        const double lc[3]={lc0,lc1,lc2}, nv[3]={nv0,nv1,nv2};
        const double co[3]={co0,co1,co2};
        double lbox = 0.0, lobj = 0.0, lcls = 0.0;
        #pragma unroll
        for (int l = 0; l < 3; ++l) {
            const double nvv = fmax(nv[l], 1.0);
            lbox += lb[l] / nvv;
            lcls += lc[l] / (nvv * (double)NCLS);
            const double N = (double)((BATCH * NA * 6400) >> (2*l));
            lobj += (so[l] - co[l]) / N;
        }
        lbox *= 0.05;
        lcls *= 0.5;
        const double loss = lbox + lobj + lcls;
        out[0] = (float)loss;
        out[1] = (float)lbox;
        out[2] = (float)lobj;
        out[3] = (float)lcls;
        out[4] = (float)loss;
    }
}

extern "C" void kernel_launch(void* const* d_in, const int* in_sizes, int n_in,
                              void* d_out, int out_size, void* d_ws, size_t ws_size,
                              hipStream_t stream) {
    const float* p0      = (const float*)d_in[0];
    const float* p1      = (const float*)d_in[1];
    const float* p2      = (const float*)d_in[2];
    const float* targets = (const float*)d_in[3];
    const float* anchors = (const float*)d_in[4];

    main_kernel<<<NBLK, 256, 0, stream>>>(p0, p1, p2, targets, anchors,
                                          (char*)d_ws);
    final_kernel<<<1, 64, 0, stream>>>((const char*)d_ws, (float*)d_out);
}